// Round 7
// baseline (960.446 us; speedup 1.0000x reference)
//
#include <hip/hip_runtime.h>

// UpsampleRFFT (zero-insert 2x + ideal half-band low-pass, circular), closed form:
//   g[j] = sign*cot(pi*(2j+1)/256)/128, sign=+ if j even
//   out[2r][2i]   = x[r][i] (exact fp32)      out[2r][2i+1] = T[r][i],  T = X*G
//   out[2p+1][c]  = sum_m g[(p-m)&127] * E[m][c],  E = even rows
// 2 blocks per image (output-column halves) so LDS = 35KB -> 4 blocks/CU.
// Phase A: T via MFMA (row-resident X, transposed GEMM), writes even rows to
// global and E^T (bf16) into LDS. Phase B: odd rows = G*E from LDS E^T.
// Tap frags (8/lane, A/B-role-shared, R2-verified lane/k convention) in d_ws.
// R5/R6 lesson (rule #20): persistent union{vector;array} xa[4] was allocated
// in SCRATCH (symmetric FETCH/WRITE inflation ~+90MB, 5x serialization).
// Build fragments via a transient per-iteration union like R4 (proven 60 VGPR).

typedef __bf16 bf16x8 __attribute__((ext_vector_type(8)));
typedef float  f32x4  __attribute__((ext_vector_type(4)));

#define W2 136        // Et pitch in bf16: 272B rows, 16B-aligned
#define PI_F 3.14159265358979323846f

__device__ __forceinline__ unsigned short f2bf(float x) {
    unsigned int b = __float_as_uint(x);
    return (unsigned short)((b + 0x7FFFu + ((b >> 16) & 1u)) >> 16);  // RNE
}

__device__ __forceinline__ float gfun(int j) {           // g[j & 127]
    int d = 2 * (j & 127) + 1;
    float th = PI_F * (float)d * (1.0f / 256.0f);
    float s  = ((d & 3) == 1) ? 1.0f : -1.0f;
    return s * cosf(th) / (128.0f * sinf(th));
}

// ---- init: per-lane tap fragment table (8 frags x 64 lanes x 8 bf16 = 8KB) ----
__global__ __launch_bounds__(512)
void init_ghtab(unsigned short* __restrict__ ghtab)
{
    const int t    = threadIdx.x;         // t = dd*64 + lane
    const int lane = t & 63;
    const int l15  = lane & 15;
    const int l4   = lane >> 4;
    const int dd   = t >> 6;
    const int base = l15 - 8 * l4 + 16 * dd;
    unsigned short u[8];
    #pragma unroll
    for (int e = 0; e < 8; ++e) u[e] = f2bf(gfun(base - e));
    *(ushort4*)&ghtab[t * 8]     = make_ushort4(u[0], u[1], u[2], u[3]);
    *(ushort4*)&ghtab[t * 8 + 4] = make_ushort4(u[4], u[5], u[6], u[7]);
}

// ---- fused kernel: 2 blocks/image (c-halves), 512 threads (8 waves) ----
__global__ __launch_bounds__(512, 4)
void upsample_fused(const float* __restrict__ xin, float* __restrict__ out,
                    const unsigned short* __restrict__ ghtab)
{
    __shared__ __align__(16) __bf16 Et[128 * W2];  // Et[c_local][m] = E[m][128*cb+c]
    __shared__ float gtab[128];                    // fallback only

    const int tid  = threadIdx.x;
    const int lane = tid & 63;
    const int w    = tid >> 6;        // 0..7: r-tile (A) and p-tile (B)
    const int l15  = lane & 15;
    const int l4   = lane >> 4;

    // XCD-swizzle: both c-halves of an image land on the same XCD (L2 x-reuse).
    const int bid = blockIdx.x;
    const long long img = (long long)((bid & 7) | ((bid >> 4) << 3));
    const int cb        = (bid >> 3) & 1;          // column half
    const float* __restrict__ xim = xin + img * (128LL * 128LL);
    float*       __restrict__ oim = out + img * (256LL * 256LL);

    const int r = 16 * w + l15;
    const float* __restrict__ xrow = xim + r * 128;

    // issue full-row x loads first (K=128 needed for the W-conv)
    float4 xlo[4], xhi[4];
    #pragma unroll
    for (int t = 0; t < 4; ++t) {
        xlo[t] = *(const float4*)&xrow[32 * t + 8 * l4];
        xhi[t] = *(const float4*)&xrow[32 * t + 8 * l4 + 4];
    }

    // tap fragments: 8 coalesced 16B loads from precomputed table
    bf16x8 gh[8];
    if (ghtab) {
        #pragma unroll
        for (int dd = 0; dd < 8; ++dd)
            gh[dd] = *(const bf16x8*)&ghtab[(dd * 64 + lane) * 8];
    } else {
        if (tid < 128) gtab[tid] = gfun(tid);
        __syncthreads();
        #pragma unroll
        for (int dd = 0; dd < 8; ++dd) {
            union { bf16x8 v; unsigned short u[8]; } H;
            int base = l15 - 8 * l4 + 16 * dd;
            #pragma unroll
            for (int e = 0; e < 8; ++e) H.u[e] = f2bf(gtab[(base - e) & 127]);
            gh[dd] = H.v;
        }
    }

    // X fragments: transient union per t (register-resident, R4-proven pattern);
    // even cols of E^T for this c-half written in the same pass.
    bf16x8 xa[4];
    #pragma unroll
    for (int t = 0; t < 4; ++t) {
        union { bf16x8 v; unsigned short u[8]; } H;
        H.u[0] = f2bf(xlo[t].x); H.u[1] = f2bf(xlo[t].y);
        H.u[2] = f2bf(xlo[t].z); H.u[3] = f2bf(xlo[t].w);
        H.u[4] = f2bf(xhi[t].x); H.u[5] = f2bf(xhi[t].y);
        H.u[6] = f2bf(xhi[t].z); H.u[7] = f2bf(xhi[t].w);
        xa[t] = H.v;
        if ((t >> 1) == cb) {                      // this t covers our c-half
            const int tt = t & 1;
            unsigned short* Eu = (unsigned short*)Et;
            #pragma unroll
            for (int e = 0; e < 8; ++e)
                Eu[(64 * tt + 16 * l4 + 2 * e) * W2 + r] = H.u[e];
        }
    }

    // ---- phase A: T = X*G (transposed); even output rows + odd cols of E^T ----
    float* __restrict__ orow = oim + (2 * r) * 256 + 128 * cb;
    #pragma unroll
    for (int mt = 0; mt < 4; ++mt) {
        f32x4 acc = {0.f, 0.f, 0.f, 0.f};
        #pragma unroll
        for (int t = 0; t < 4; ++t)
            acc = __builtin_amdgcn_mfma_f32_16x16x32_bf16(gh[(4 * cb + mt - 2 * t) & 7],
                                                          xa[t], acc, 0, 0, 0);
        const int i0l = 16 * mt + 4 * l4;          // local i in [0,64)
        float4 xc = *(const float4*)&xrow[64 * cb + i0l];   // L1 hit, exact fp32
        float4 o0 = make_float4(xc.x, acc[0], xc.y, acc[1]);
        float4 o1 = make_float4(xc.z, acc[2], xc.w, acc[3]);
        *(float4*)&orow[2 * i0l]     = o0;
        *(float4*)&orow[2 * i0l + 4] = o1;
        unsigned short* Eu = (unsigned short*)Et;
        #pragma unroll
        for (int q = 0; q < 4; ++q)
            Eu[(2 * (i0l + q) + 1) * W2 + r] = f2bf(acc[q]);
    }
    __syncthreads();

    // ---- phase B: odd[p][c] = sum_m g[(p-m)&127] * E[m][c] ----
    {
        float* __restrict__ prow = oim + (2 * (16 * w + l15) + 1) * 256 + 128 * cb;
        #pragma unroll
        for (int mc = 0; mc < 8; ++mc) {
            f32x4 acc = {0.f, 0.f, 0.f, 0.f};
            #pragma unroll
            for (int t = 0; t < 4; ++t) {
                bf16x8 ef = *(const bf16x8*)&Et[(16 * mc + l15) * W2 + 32 * t + 8 * l4];
                acc = __builtin_amdgcn_mfma_f32_16x16x32_bf16(ef, gh[(w - 2 * t) & 7],
                                                              acc, 0, 0, 0);
            }
            float4 o = make_float4(acc[0], acc[1], acc[2], acc[3]);
            *(float4*)&prow[16 * mc + 4 * l4] = o;   // p=16w+l15, c=16mc+4l4+q
        }
    }
}

extern "C" void kernel_launch(void* const* d_in, const int* in_sizes, int n_in,
                              void* d_out, int out_size, void* d_ws, size_t ws_size,
                              hipStream_t stream)
{
    (void)n_in; (void)out_size;
    const float* x = (const float*)d_in[0];
    float* out = (float*)d_out;
    int nimg = in_sizes[0] / (128 * 128);   // 1024 images

    unsigned short* ghtab = nullptr;
    if (ws_size >= 8192) {
        ghtab = (unsigned short*)d_ws;
        hipLaunchKernelGGL(init_ghtab, dim3(1), dim3(512), 0, stream, ghtab);
    }
    hipLaunchKernelGGL(upsample_fused, dim3(nimg * 2), dim3(512), 0, stream, x, out, ghtab);
}

// Round 8
// 96.922 us; speedup vs baseline: 9.9095x; 9.9095x over previous
//
#include <hip/hip_runtime.h>

// UpsampleRFFT (zero-insert 2x + ideal half-band low-pass, circular), closed form:
//   g[j] = sign*cot(pi*(2j+1)/256)/128, sign=+ if j even
//   out[2r][2i]   = x[r][i] (exact fp32)      out[2r][2i+1] = T[r][i],  T = X*G
//   out[2p+1][c]  = sum_m g[(p-m)&127] * E[m][c],  E = even rows
// 2 blocks per image (output-column halves), LDS = 34.8KB. Phase A: T via MFMA
// (row-resident X), writes even rows + E^T (bf16) to LDS. Phase B: odd = G*E.
//
// R5-R7 lesson (rule #20): gh[(4*cb+mt-2t)&7] / gh[(w-2t)&7] are RUNTIME-indexed
// register arrays -> whole frag array in scratch -> latency-serialized (960us,
// all pipes idle). Fix: runtime offsets go into LOAD ADDRESSES, never register
// indices. ghc[v]=table[(v+4cb)&7] so phase A indexes (mt-2t)&7 (static);
// phase B loads its 4 per-wave frags at computed global addresses into gb[0..3].

typedef __bf16 bf16x8 __attribute__((ext_vector_type(8)));
typedef float  f32x4  __attribute__((ext_vector_type(4)));

#define W2 136        // Et pitch in bf16: 272B rows, 16B-aligned
#define PI_F 3.14159265358979323846f

__device__ __forceinline__ unsigned short f2bf(float x) {
    unsigned int b = __float_as_uint(x);
    return (unsigned short)((b + 0x7FFFu + ((b >> 16) & 1u)) >> 16);  // RNE
}

__device__ __forceinline__ float gfun(int j) {           // g[j & 127]
    int d = 2 * (j & 127) + 1;
    float th = PI_F * (float)d * (1.0f / 256.0f);
    float s  = ((d & 3) == 1) ? 1.0f : -1.0f;
    return s * cosf(th) / (128.0f * sinf(th));
}

// ---- init: per-lane tap fragment table (8 frags x 64 lanes x 8 bf16 = 8KB) ----
__global__ __launch_bounds__(512)
void init_ghtab(unsigned short* __restrict__ ghtab)
{
    const int t    = threadIdx.x;         // t = dd*64 + lane
    const int lane = t & 63;
    const int l15  = lane & 15;
    const int l4   = lane >> 4;
    const int dd   = t >> 6;
    const int base = l15 - 8 * l4 + 16 * dd;
    unsigned short u[8];
    #pragma unroll
    for (int e = 0; e < 8; ++e) u[e] = f2bf(gfun(base - e));
    *(ushort4*)&ghtab[t * 8]     = make_ushort4(u[0], u[1], u[2], u[3]);
    *(ushort4*)&ghtab[t * 8 + 4] = make_ushort4(u[4], u[5], u[6], u[7]);
}

// ---- fused kernel: 2 blocks/image (c-halves), 512 threads (8 waves) ----
__global__ __launch_bounds__(512, 4)
void upsample_fused(const float* __restrict__ xin, float* __restrict__ out,
                    const unsigned short* __restrict__ ghtab)
{
    __shared__ __align__(16) unsigned short Et[128 * W2]; // Et[c_loc][r], bf16 bits

    const int tid  = threadIdx.x;
    const int lane = tid & 63;
    const int w    = tid >> 6;        // 0..7: r-tile (A) and p-tile (B)
    const int l15  = lane & 15;
    const int l4   = lane >> 4;

    const long long img = blockIdx.x >> 1;
    const int cb        = blockIdx.x & 1;          // column half
    const float* __restrict__ xim = xin + img * (128LL * 128LL);
    float*       __restrict__ oim = out + img * (256LL * 256LL);

    const int r = 16 * w + l15;
    const float* __restrict__ xrow = xim + r * 128;

    // issue full-row x loads first (K=128 needed for the W-conv)
    float4 xlo[4], xhi[4];
    #pragma unroll
    for (int t = 0; t < 4; ++t) {
        xlo[t] = *(const float4*)&xrow[32 * t + 8 * l4];
        xhi[t] = *(const float4*)&xrow[32 * t + 8 * l4 + 4];
    }

    // Phase-A tap frags: cb folded into the ADDRESS, so all register indices
    // below are compile-time. ghc[v] = frag[(v + 4cb) & 7].
    bf16x8 ghc[8];
    #pragma unroll
    for (int v = 0; v < 8; ++v) {
        const int dd = (v + 4 * cb) & 7;
        ghc[v] = *(const bf16x8*)&ghtab[(dd * 64 + lane) * 8];
    }

    // X fragments (transient union, register-resident) + even cols of E^T.
    bf16x8 xa[4];
    #pragma unroll
    for (int t = 0; t < 4; ++t) {
        union { bf16x8 v; unsigned short u[8]; } H;
        H.u[0] = f2bf(xlo[t].x); H.u[1] = f2bf(xlo[t].y);
        H.u[2] = f2bf(xlo[t].z); H.u[3] = f2bf(xlo[t].w);
        H.u[4] = f2bf(xhi[t].x); H.u[5] = f2bf(xhi[t].y);
        H.u[6] = f2bf(xhi[t].z); H.u[7] = f2bf(xhi[t].w);
        xa[t] = H.v;
        if ((t >> 1) == cb) {                      // this t covers our c-half
            const int tt = t & 1;
            #pragma unroll
            for (int e = 0; e < 8; ++e)
                Et[(64 * tt + 16 * l4 + 2 * e) * W2 + r] = H.u[e];
        }
    }

    // ---- phase A: T = X*G (transposed); even output rows + odd cols of E^T ----
    float* __restrict__ orow = oim + (2 * r) * 256 + 128 * cb;
    #pragma unroll
    for (int mt = 0; mt < 4; ++mt) {
        f32x4 acc = {0.f, 0.f, 0.f, 0.f};
        #pragma unroll
        for (int t = 0; t < 4; ++t)
            acc = __builtin_amdgcn_mfma_f32_16x16x32_bf16(ghc[(mt - 2 * t) & 7],
                                                          xa[t], acc, 0, 0, 0);
        const int i0l = 16 * mt + 4 * l4;          // local i in [0,64)
        float4 xc = *(const float4*)&xrow[64 * cb + i0l];   // L1 hit, exact fp32
        float4 o0 = make_float4(xc.x, acc[0], xc.y, acc[1]);
        float4 o1 = make_float4(xc.z, acc[2], xc.w, acc[3]);
        *(float4*)&orow[2 * i0l]     = o0;
        *(float4*)&orow[2 * i0l + 4] = o1;
        #pragma unroll
        for (int q = 0; q < 4; ++q)
            Et[(2 * (i0l + q) + 1) * W2 + r] = f2bf(acc[q]);
    }
    __syncthreads();

    // ---- phase B: odd[p][c] = sum_m g[(p-m)&127] * E[m][c] ----
    {
        // Per-wave B-frags loaded at runtime-computed ADDRESSES (indices static).
        bf16x8 gb[4];
        #pragma unroll
        for (int t = 0; t < 4; ++t) {
            const int dd = (w - 2 * t) & 7;
            gb[t] = *(const bf16x8*)&ghtab[(dd * 64 + lane) * 8];
        }
        float* __restrict__ prow = oim + (2 * (16 * w + l15) + 1) * 256 + 128 * cb;
        #pragma unroll
        for (int mc = 0; mc < 8; ++mc) {
            f32x4 acc = {0.f, 0.f, 0.f, 0.f};
            #pragma unroll
            for (int t = 0; t < 4; ++t) {
                bf16x8 ef = *(const bf16x8*)&Et[(16 * mc + l15) * W2 + 32 * t + 8 * l4];
                acc = __builtin_amdgcn_mfma_f32_16x16x32_bf16(ef, gb[t], acc, 0, 0, 0);
            }
            float4 o = make_float4(acc[0], acc[1], acc[2], acc[3]);
            *(float4*)&prow[16 * mc + 4 * l4] = o;   // p=16w+l15, c=16mc+4l4+q
        }
    }
}

extern "C" void kernel_launch(void* const* d_in, const int* in_sizes, int n_in,
                              void* d_out, int out_size, void* d_ws, size_t ws_size,
                              hipStream_t stream)
{
    (void)n_in; (void)out_size; (void)ws_size;
    const float* x = (const float*)d_in[0];
    float* out = (float*)d_out;
    int nimg = in_sizes[0] / (128 * 128);   // 1024 images

    unsigned short* ghtab = (unsigned short*)d_ws;   // needs 8KB; ws is ample
    hipLaunchKernelGGL(init_ghtab, dim3(1), dim3(512), 0, stream, ghtab);
    hipLaunchKernelGGL(upsample_fused, dim3(nimg * 2), dim3(512), 0, stream, x, out, ghtab);
}